// Round 3
// baseline (9753.271 us; speedup 1.0000x reference)
//
#include <hip/hip_runtime.h>
#include <hip/hip_bf16.h>

#define Bz 4
#define Sz 2048
#define Dz 1024
#define Hz 16
#define DHz 64

typedef __bf16 bf16x8 __attribute__((ext_vector_type(8)));
typedef float f32x4 __attribute__((ext_vector_type(4)));

// fp32 -> bf16 elementwise cast (RTN), n % 4 == 0.
__global__ __launch_bounds__(256) void cvt_f32_bf16(const float* __restrict__ src,
                                                    __hip_bfloat16* __restrict__ dst, int n) {
    int i = (blockIdx.x * 256 + threadIdx.x) * 4;
    if (i >= n) return;
    float4 f = *reinterpret_cast<const float4*>(src + i);
    dst[i + 0] = __float2bfloat16(f.x);
    dst[i + 1] = __float2bfloat16(f.y);
    dst[i + 2] = __float2bfloat16(f.z);
    dst[i + 3] = __float2bfloat16(f.w);
}

// C[M,N] = A[M,K] @ W[N,K]^T   (bf16 in, OT out, fp32 accum)
// One wave computes a 16x64 tile: 4 column sub-tiles of 16x16 via mfma_f32_16x16x32_bf16.
// A-frag: lane holds A[m=lane&15][k=(lane>>4)*8 + j]   (forced by dims: lane&15 -> m(16), quad*8+j -> k(32))
// B-frag: lane holds W[n=lane&15][k=(lane>>4)*8 + j]
// C/D   : reg r of lane -> row=(lane>>4)*4+r, col=lane&15   [verified, learn_hip m89/m91]
template <int M, int N, int K, typename OT>
__global__ __launch_bounds__(256) void gemm_bt(const __hip_bfloat16* __restrict__ A,
                                               const __hip_bfloat16* __restrict__ W,
                                               OT* __restrict__ C) {
    const int wave = (blockIdx.x << 2) + (threadIdx.x >> 6);
    const int lane = threadIdx.x & 63;
    constexpr int NT = N / 64;
    const int mt = wave / NT;
    const int nt = wave % NT;
    const int r16 = lane & 15;
    const int quad = lane >> 4;

    const __hip_bfloat16* Arow = A + (size_t)(mt * 16 + r16) * K + quad * 8;
    const __hip_bfloat16* Wrow = W + (size_t)(nt * 64 + r16) * K + quad * 8;

    f32x4 acc0 = {0.f, 0.f, 0.f, 0.f};
    f32x4 acc1 = {0.f, 0.f, 0.f, 0.f};
    f32x4 acc2 = {0.f, 0.f, 0.f, 0.f};
    f32x4 acc3 = {0.f, 0.f, 0.f, 0.f};

#pragma unroll 4
    for (int k0 = 0; k0 < K; k0 += 32) {
        bf16x8 a  = *reinterpret_cast<const bf16x8*>(Arow + k0);
        bf16x8 b0 = *reinterpret_cast<const bf16x8*>(Wrow + k0);
        bf16x8 b1 = *reinterpret_cast<const bf16x8*>(Wrow + (size_t)16 * K + k0);
        bf16x8 b2 = *reinterpret_cast<const bf16x8*>(Wrow + (size_t)32 * K + k0);
        bf16x8 b3 = *reinterpret_cast<const bf16x8*>(Wrow + (size_t)48 * K + k0);
        acc0 = __builtin_amdgcn_mfma_f32_16x16x32_bf16(a, b0, acc0, 0, 0, 0);
        acc1 = __builtin_amdgcn_mfma_f32_16x16x32_bf16(a, b1, acc1, 0, 0, 0);
        acc2 = __builtin_amdgcn_mfma_f32_16x16x32_bf16(a, b2, acc2, 0, 0, 0);
        acc3 = __builtin_amdgcn_mfma_f32_16x16x32_bf16(a, b3, acc3, 0, 0, 0);
    }

    const size_t c0 = (size_t)(mt * 16 + quad * 4) * N + nt * 64 + r16;
#pragma unroll
    for (int r = 0; r < 4; ++r) {
        if constexpr (__is_same(OT, float)) {
            C[c0 + (size_t)r * N +  0] = acc0[r];
            C[c0 + (size_t)r * N + 16] = acc1[r];
            C[c0 + (size_t)r * N + 32] = acc2[r];
            C[c0 + (size_t)r * N + 48] = acc3[r];
        } else {
            C[c0 + (size_t)r * N +  0] = __float2bfloat16(acc0[r]);
            C[c0 + (size_t)r * N + 16] = __float2bfloat16(acc1[r]);
            C[c0 + (size_t)r * N + 32] = __float2bfloat16(acc2[r]);
            C[c0 + (size_t)r * N + 48] = __float2bfloat16(acc3[r]);
        }
    }
}

// Flash-style causal attention, online softmax.
// One wave per (b,h,q) row; lane = head-dim element (DH==64==wave width).
__global__ __launch_bounds__(256) void attn_rowwave(const __hip_bfloat16* __restrict__ Q,
                                                    const __hip_bfloat16* __restrict__ Kt,
                                                    const __hip_bfloat16* __restrict__ V,
                                                    __hip_bfloat16* __restrict__ O) {
    const int w    = blockIdx.x * 4 + (threadIdx.x >> 6);
    const int lane = threadIdx.x & 63;
    const int q  = w % Sz;
    const int bh = w / Sz;
    const int h  = bh % Hz;
    const int b  = bh / Hz;

    const size_t head_base = (size_t)b * Sz * Dz + (size_t)h * DHz + lane;
    const float qv = __bfloat162float(Q[head_base + (size_t)q * Dz]);

    const __hip_bfloat16* Kp = Kt + head_base;
    const __hip_bfloat16* Vp = V + head_base;

    float m = -1e30f, l = 0.f, o = 0.f;
    for (int k = 0; k <= q; ++k) {
        float kv = __bfloat162float(Kp[(size_t)k * Dz]);
        float s = qv * kv;
#pragma unroll
        for (int off = 32; off > 0; off >>= 1) s += __shfl_xor(s, off, 64);
        s *= 0.125f;  // 1/sqrt(64)
        float vv = __bfloat162float(Vp[(size_t)k * Dz]);
        if (s <= m) {                      // wave-uniform branch (s,m uniform)
            float p = __expf(s - m);
            l += p;
            o = fmaf(p, vv, o);
        } else {
            float alpha = __expf(m - s);   // first iter: exp(-1e30)=0
            l = l * alpha + 1.f;           // p = exp(0) = 1
            o = fmaf(o, alpha, vv);
            m = s;
        }
    }
    O[head_base + (size_t)q * Dz] = __float2bfloat16(o / l);
}

extern "C" void kernel_launch(void* const* d_in, const int* in_sizes, int n_in,
                              void* d_out, int out_size, void* d_ws, size_t ws_size,
                              hipStream_t stream) {
    // Inputs fp32, output fp32 (reference dtypes). Internal compute bf16.
    const float* x  = (const float*)d_in[0];
    const float* wq = (const float*)d_in[1];
    const float* wk = (const float*)d_in[2];
    const float* wv = (const float*)d_in[3];
    const float* wo = (const float*)d_in[4];
    float* out = (float*)d_out;

    constexpr int TOK = Bz * Sz * Dz;   // 8,388,608
    constexpr int WEL = Dz * Dz;        // 1,048,576

    // ws layout (bf16 elements): xb | wqb | wkb | wvb | wob | Qb | Kb   (56 MB)
    // Vb lives in d_out's first 16 MB (dead before final GEMM overwrites d_out).
    // Ob aliases xb (x dead after QKV GEMMs). All same-stream ordered.
    __hip_bfloat16* xb  = (__hip_bfloat16*)d_ws;
    __hip_bfloat16* wqb = xb  + TOK;
    __hip_bfloat16* wkb = wqb + WEL;
    __hip_bfloat16* wvb = wkb + WEL;
    __hip_bfloat16* wob = wvb + WEL;
    __hip_bfloat16* Qb  = wob + WEL;
    __hip_bfloat16* Kb  = Qb + TOK;
    __hip_bfloat16* Vb  = (__hip_bfloat16*)d_out;  // scratch: first 16 MB of the 32 MB out buf
    __hip_bfloat16* Ob  = xb;                      // alias

    cvt_f32_bf16<<<TOK / 4 / 256, 256, 0, stream>>>(x,  xb,  TOK);
    cvt_f32_bf16<<<WEL / 4 / 256, 256, 0, stream>>>(wq, wqb, WEL);
    cvt_f32_bf16<<<WEL / 4 / 256, 256, 0, stream>>>(wk, wkb, WEL);
    cvt_f32_bf16<<<WEL / 4 / 256, 256, 0, stream>>>(wv, wvb, WEL);
    cvt_f32_bf16<<<WEL / 4 / 256, 256, 0, stream>>>(wo, wob, WEL);

    constexpr int M = Bz * Sz;                              // 8192
    constexpr int GEMM_BLOCKS = (M / 16) * (Dz / 64) / 4;   // 2048

    gemm_bt<M, Dz, Dz, __hip_bfloat16><<<GEMM_BLOCKS, 256, 0, stream>>>(xb, wqb, Qb);
    gemm_bt<M, Dz, Dz, __hip_bfloat16><<<GEMM_BLOCKS, 256, 0, stream>>>(xb, wkb, Kb);
    gemm_bt<M, Dz, Dz, __hip_bfloat16><<<GEMM_BLOCKS, 256, 0, stream>>>(xb, wvb, Vb);

    const int ATTN_BLOCKS = Bz * Hz * Sz / 4;  // 32768
    attn_rowwave<<<ATTN_BLOCKS, 256, 0, stream>>>(Qb, Kb, Vb, Ob);

    gemm_bt<M, Dz, Dz, float><<<GEMM_BLOCKS, 256, 0, stream>>>(Ob, wob, out);
}

// Round 4
// 1011.193 us; speedup vs baseline: 9.6453x; 9.6453x over previous
//
#include <hip/hip_runtime.h>
#include <hip/hip_bf16.h>

#define Bz 4
#define Sz 2048
#define Dz 1024
#define Hz 16
#define DHz 64

typedef __bf16 bf16x8 __attribute__((ext_vector_type(8)));
typedef float f32x4 __attribute__((ext_vector_type(4)));

// fp32 -> bf16 elementwise cast (RTN), n % 4 == 0.
__global__ __launch_bounds__(256) void cvt_f32_bf16(const float* __restrict__ src,
                                                    __hip_bfloat16* __restrict__ dst, int n) {
    int i = (blockIdx.x * 256 + threadIdx.x) * 4;
    if (i >= n) return;
    float4 f = *reinterpret_cast<const float4*>(src + i);
    dst[i + 0] = __float2bfloat16(f.x);
    dst[i + 1] = __float2bfloat16(f.y);
    dst[i + 2] = __float2bfloat16(f.z);
    dst[i + 3] = __float2bfloat16(f.w);
}

// C[M,N] = A[M,K] @ W[N,K]^T   (bf16 in, OT out, fp32 accum)
// A-frag: lane holds A[m=lane&15][k=quad*8+j]; B-frag: W[n=lane&15][k=quad*8+j]
// C/D: reg r -> row=quad*4+r, col=lane&15   [verified R3, learn_hip m89/m91]
template <int M, int N, int K, typename OT>
__global__ __launch_bounds__(256) void gemm_bt(const __hip_bfloat16* __restrict__ A,
                                               const __hip_bfloat16* __restrict__ W,
                                               OT* __restrict__ C) {
    const int wave = (blockIdx.x << 2) + (threadIdx.x >> 6);
    const int lane = threadIdx.x & 63;
    constexpr int NT = N / 64;
    const int mt = wave / NT;
    const int nt = wave % NT;
    const int r16 = lane & 15;
    const int quad = lane >> 4;

    const __hip_bfloat16* Arow = A + (size_t)(mt * 16 + r16) * K + quad * 8;
    const __hip_bfloat16* Wrow = W + (size_t)(nt * 64 + r16) * K + quad * 8;

    f32x4 acc0 = {0.f, 0.f, 0.f, 0.f};
    f32x4 acc1 = {0.f, 0.f, 0.f, 0.f};
    f32x4 acc2 = {0.f, 0.f, 0.f, 0.f};
    f32x4 acc3 = {0.f, 0.f, 0.f, 0.f};

#pragma unroll 4
    for (int k0 = 0; k0 < K; k0 += 32) {
        bf16x8 a  = *reinterpret_cast<const bf16x8*>(Arow + k0);
        bf16x8 b0 = *reinterpret_cast<const bf16x8*>(Wrow + k0);
        bf16x8 b1 = *reinterpret_cast<const bf16x8*>(Wrow + (size_t)16 * K + k0);
        bf16x8 b2 = *reinterpret_cast<const bf16x8*>(Wrow + (size_t)32 * K + k0);
        bf16x8 b3 = *reinterpret_cast<const bf16x8*>(Wrow + (size_t)48 * K + k0);
        acc0 = __builtin_amdgcn_mfma_f32_16x16x32_bf16(a, b0, acc0, 0, 0, 0);
        acc1 = __builtin_amdgcn_mfma_f32_16x16x32_bf16(a, b1, acc1, 0, 0, 0);
        acc2 = __builtin_amdgcn_mfma_f32_16x16x32_bf16(a, b2, acc2, 0, 0, 0);
        acc3 = __builtin_amdgcn_mfma_f32_16x16x32_bf16(a, b3, acc3, 0, 0, 0);
    }

    const size_t c0 = (size_t)(mt * 16 + quad * 4) * N + nt * 64 + r16;
#pragma unroll
    for (int r = 0; r < 4; ++r) {
        if constexpr (__is_same(OT, float)) {
            C[c0 + (size_t)r * N +  0] = acc0[r];
            C[c0 + (size_t)r * N + 16] = acc1[r];
            C[c0 + (size_t)r * N + 32] = acc2[r];
            C[c0 + (size_t)r * N + 48] = acc3[r];
        } else {
            C[c0 + (size_t)r * N +  0] = __float2bfloat16(acc0[r]);
            C[c0 + (size_t)r * N + 16] = __float2bfloat16(acc1[r]);
            C[c0 + (size_t)r * N + 32] = __float2bfloat16(acc2[r]);
            C[c0 + (size_t)r * N + 48] = __float2bfloat16(acc3[r]);
        }
    }
}

// MFMA flash attention (causal, online softmax).
// Block = (b, h, 64 q-rows); wave w owns q-tile [q0, q0+16).
// S^T = K·Q^T per 16-key subtile (both operands direct row loads).
// S^T C-layout: row=key=quad*4+r, col=q=lane&15 -> softmax state m,l per-lane (q).
// PV: P via per-wave LDS transpose (PT, [q][key] stride 40), V via cooperative
// transposed stage (VT, [dh][key] stride 40); both read back as ds_read_b128.
__global__ __launch_bounds__(256) void attn_mfma(const __hip_bfloat16* __restrict__ Q,
                                                 const __hip_bfloat16* __restrict__ Km,
                                                 const __hip_bfloat16* __restrict__ Vm,
                                                 __hip_bfloat16* __restrict__ O) {
    __shared__ unsigned short VT[64 * 40];      // V^T tile: [dh][key], stride 40 (80B, 16B-aligned rows)
    __shared__ unsigned short PT[4][16 * 40];   // per-wave P: [q][key], stride 40

    const int tid  = threadIdx.x;
    const int wid  = tid >> 6;
    const int lane = tid & 63;
    const int quad = lane >> 4;
    const int l16  = lane & 15;

    const int qblk = blockIdx.x & 31;           // Sz/64 = 32
    const int bh   = blockIdx.x >> 5;
    const int h    = bh & 15;
    const int b    = bh >> 4;
    const int q0   = (qblk << 6) + (wid << 4);
    const size_t base = (size_t)b * Sz * Dz + (size_t)h * DHz;

    // Q as B-operand of S^T: lane holds Q[q=q0+l16][dh=quad*8+j], dh halves 0..31 / 32..63
    const __hip_bfloat16* qp = Q + base + (size_t)(q0 + l16) * Dz + quad * 8;
    const bf16x8 qf0 = *reinterpret_cast<const bf16x8*>(qp);
    const bf16x8 qf1 = *reinterpret_cast<const bf16x8*>(qp + 32);

    float m = -1e30f, l = 0.f;
    f32x4 o0 = {0.f,0.f,0.f,0.f}, o1 = {0.f,0.f,0.f,0.f};
    f32x4 o2 = {0.f,0.f,0.f,0.f}, o3 = {0.f,0.f,0.f,0.f};

    const int kend = (qblk << 6) + 64;          // block causal limit (uniform -> uniform barriers)
    const int vkey = (tid & 15) * 2;            // V stage: thread covers keys vkey, vkey+1
    const int vdh  = (tid >> 4) * 4;            //          dh quartet
    const __hip_bfloat16* vbase = Vm + base + vdh;

    for (int k0 = 0; k0 < kend; k0 += 32) {
        __syncthreads();  // all waves done reading previous VT
        {
            const ushort4 va = *reinterpret_cast<const ushort4*>(vbase + (size_t)(k0 + vkey) * Dz);
            const ushort4 vb = *reinterpret_cast<const ushort4*>(vbase + (size_t)(k0 + vkey + 1) * Dz);
            *reinterpret_cast<ushort2*>(&VT[(vdh + 0) * 40 + vkey]) = make_ushort2(va.x, vb.x);
            *reinterpret_cast<ushort2*>(&VT[(vdh + 1) * 40 + vkey]) = make_ushort2(va.y, vb.y);
            *reinterpret_cast<ushort2*>(&VT[(vdh + 2) * 40 + vkey]) = make_ushort2(va.z, vb.z);
            *reinterpret_cast<ushort2*>(&VT[(vdh + 3) * 40 + vkey]) = make_ushort2(va.w, vb.w);
        }
        __syncthreads();

        // K rows as A-operand: lane holds K[key=k0+sub*16+l16][dh=quad*8+j]
        const __hip_bfloat16* kp = Km + base + (size_t)(k0 + l16) * Dz + quad * 8;
        const bf16x8 kf00 = *reinterpret_cast<const bf16x8*>(kp);
        const bf16x8 kf01 = *reinterpret_cast<const bf16x8*>(kp + 32);
        const bf16x8 kf10 = *reinterpret_cast<const bf16x8*>(kp + (size_t)16 * Dz);
        const bf16x8 kf11 = *reinterpret_cast<const bf16x8*>(kp + (size_t)16 * Dz + 32);

        f32x4 s0 = {0.f,0.f,0.f,0.f}, s1 = {0.f,0.f,0.f,0.f};
        s0 = __builtin_amdgcn_mfma_f32_16x16x32_bf16(kf00, qf0, s0, 0, 0, 0);
        s0 = __builtin_amdgcn_mfma_f32_16x16x32_bf16(kf01, qf1, s0, 0, 0, 0);
        s1 = __builtin_amdgcn_mfma_f32_16x16x32_bf16(kf10, qf0, s1, 0, 0, 0);
        s1 = __builtin_amdgcn_mfma_f32_16x16x32_bf16(kf11, qf1, s1, 0, 0, 0);

        // mask + scale; S^T element: key=k0+(sub*16)+quad*4+r, q=q0+l16
        const int qrow = q0 + l16;
        float sv[8];
        float tmax = -1e30f;
#pragma unroll
        for (int r = 0; r < 4; ++r) {
            const int key0 = k0 + quad * 4 + r;
            sv[r]     = (key0      <= qrow) ? s0[r] * 0.125f : -1e30f;
            sv[4 + r] = (key0 + 16 <= qrow) ? s1[r] * 0.125f : -1e30f;
            tmax = fmaxf(tmax, fmaxf(sv[r], sv[4 + r]));
        }
        tmax = fmaxf(tmax, __shfl_xor(tmax, 16, 64));
        tmax = fmaxf(tmax, __shfl_xor(tmax, 32, 64));
        const float mnew = fmaxf(m, tmax);
        const float alpha = __expf(m - mnew);   // first tile: exp(-1e30)=0
        m = mnew;

        float psum = 0.f;
        unsigned short pb[8];
#pragma unroll
        for (int i = 0; i < 8; ++i) {
            const float p = __expf(sv[i] - mnew);
            psum += p;
            union { __hip_bfloat16 h; unsigned short u; } cv;
            cv.h = __float2bfloat16(p);
            pb[i] = cv.u;
        }
        psum += __shfl_xor(psum, 16, 64);
        psum += __shfl_xor(psum, 32, 64);
        l = l * alpha + psum;

        // P^T (C-layout) -> PT[wid] as [q][key]: keys quad*4+r consecutive -> 8B packed writes
        *reinterpret_cast<ushort4*>(&PT[wid][l16 * 40 + quad * 4])      = make_ushort4(pb[0], pb[1], pb[2], pb[3]);
        *reinterpret_cast<ushort4*>(&PT[wid][l16 * 40 + 16 + quad * 4]) = make_ushort4(pb[4], pb[5], pb[6], pb[7]);

        // rescale O (row = q = quad*4+r -> broadcast alpha from lane quad*4+r)
#pragma unroll
        for (int r = 0; r < 4; ++r) {
            const float ar = __shfl(alpha, quad * 4 + r, 64);
            o0[r] *= ar; o1[r] *= ar; o2[r] *= ar; o3[r] *= ar;
        }

        // PV: A-frag = P[q=l16][key=quad*8+j], B-frags = V[key=quad*8+j][dh=t*16+l16] via VT
        const bf16x8 pa  = *reinterpret_cast<const bf16x8*>(&PT[wid][l16 * 40 + quad * 8]);
        const bf16x8 vf0 = *reinterpret_cast<const bf16x8*>(&VT[(     l16) * 40 + quad * 8]);
        const bf16x8 vf1 = *reinterpret_cast<const bf16x8*>(&VT[(16 + l16) * 40 + quad * 8]);
        const bf16x8 vf2 = *reinterpret_cast<const bf16x8*>(&VT[(32 + l16) * 40 + quad * 8]);
        const bf16x8 vf3 = *reinterpret_cast<const bf16x8*>(&VT[(48 + l16) * 40 + quad * 8]);
        o0 = __builtin_amdgcn_mfma_f32_16x16x32_bf16(pa, vf0, o0, 0, 0, 0);
        o1 = __builtin_amdgcn_mfma_f32_16x16x32_bf16(pa, vf1, o1, 0, 0, 0);
        o2 = __builtin_amdgcn_mfma_f32_16x16x32_bf16(pa, vf2, o2, 0, 0, 0);
        o3 = __builtin_amdgcn_mfma_f32_16x16x32_bf16(pa, vf3, o3, 0, 0, 0);
    }

    // epilogue: O row q=q0+quad*4+r, col dh=t*16+l16
#pragma unroll
    for (int r = 0; r < 4; ++r) {
        const float linv = 1.f / __shfl(l, quad * 4 + r, 64);
        __hip_bfloat16* op = O + base + (size_t)(q0 + quad * 4 + r) * Dz + l16;
        op[0]  = __float2bfloat16(o0[r] * linv);
        op[16] = __float2bfloat16(o1[r] * linv);
        op[32] = __float2bfloat16(o2[r] * linv);
        op[48] = __float2bfloat16(o3[r] * linv);
    }
}

extern "C" void kernel_launch(void* const* d_in, const int* in_sizes, int n_in,
                              void* d_out, int out_size, void* d_ws, size_t ws_size,
                              hipStream_t stream) {
    // Inputs fp32, output fp32. Internal compute bf16.
    const float* x  = (const float*)d_in[0];
    const float* wq = (const float*)d_in[1];
    const float* wk = (const float*)d_in[2];
    const float* wv = (const float*)d_in[3];
    const float* wo = (const float*)d_in[4];
    float* out = (float*)d_out;

    constexpr int TOK = Bz * Sz * Dz;   // 8,388,608
    constexpr int WEL = Dz * Dz;        // 1,048,576

    // ws: xb | wqb | wkb | wvb | wob | Qb | Kb  (56 MB). Vb in d_out scratch; Ob aliases xb.
    __hip_bfloat16* xb  = (__hip_bfloat16*)d_ws;
    __hip_bfloat16* wqb = xb  + TOK;
    __hip_bfloat16* wkb = wqb + WEL;
    __hip_bfloat16* wvb = wkb + WEL;
    __hip_bfloat16* wob = wvb + WEL;
    __hip_bfloat16* Qb  = wob + WEL;
    __hip_bfloat16* Kb  = Qb + TOK;
    __hip_bfloat16* Vb  = (__hip_bfloat16*)d_out;  // dead before final GEMM overwrites d_out
    __hip_bfloat16* Ob  = xb;                      // x dead after QKV GEMMs

    cvt_f32_bf16<<<TOK / 4 / 256, 256, 0, stream>>>(x,  xb,  TOK);
    cvt_f32_bf16<<<WEL / 4 / 256, 256, 0, stream>>>(wq, wqb, WEL);
    cvt_f32_bf16<<<WEL / 4 / 256, 256, 0, stream>>>(wk, wkb, WEL);
    cvt_f32_bf16<<<WEL / 4 / 256, 256, 0, stream>>>(wv, wvb, WEL);
    cvt_f32_bf16<<<WEL / 4 / 256, 256, 0, stream>>>(wo, wob, WEL);

    constexpr int M = Bz * Sz;                              // 8192
    constexpr int GEMM_BLOCKS = (M / 16) * (Dz / 64) / 4;   // 2048

    gemm_bt<M, Dz, Dz, __hip_bfloat16><<<GEMM_BLOCKS, 256, 0, stream>>>(xb, wqb, Qb);
    gemm_bt<M, Dz, Dz, __hip_bfloat16><<<GEMM_BLOCKS, 256, 0, stream>>>(xb, wkb, Kb);
    gemm_bt<M, Dz, Dz, __hip_bfloat16><<<GEMM_BLOCKS, 256, 0, stream>>>(xb, wvb, Vb);

    const int ATTN_BLOCKS = Bz * Hz * (Sz / 64);  // 2048
    attn_mfma<<<ATTN_BLOCKS, 256, 0, stream>>>(Qb, Kb, Vb, Ob);

    gemm_bt<M, Dz, Dz, float><<<GEMM_BLOCKS, 256, 0, stream>>>(Ob, wob, out);
}

// Round 5
// 394.284 us; speedup vs baseline: 24.7367x; 2.5646x over previous
//
#include <hip/hip_runtime.h>
#include <hip/hip_bf16.h>

#define Bz 4
#define Sz 2048
#define Dz 1024
#define Hz 16
#define DHz 64

typedef __bf16 bf16x8 __attribute__((ext_vector_type(8)));
typedef float f32x4 __attribute__((ext_vector_type(4)));

// fp32 -> bf16 elementwise cast (RTN), n % 4 == 0.
__global__ __launch_bounds__(256) void cvt_f32_bf16(const float* __restrict__ src,
                                                    __hip_bfloat16* __restrict__ dst, int n) {
    int i = (blockIdx.x * 256 + threadIdx.x) * 4;
    if (i >= n) return;
    float4 f = *reinterpret_cast<const float4*>(src + i);
    dst[i + 0] = __float2bfloat16(f.x);
    dst[i + 1] = __float2bfloat16(f.y);
    dst[i + 2] = __float2bfloat16(f.z);
    dst[i + 3] = __float2bfloat16(f.w);
}

// async global -> LDS, 16 bytes per lane; LDS dest = uniform base + lane*16.
__device__ __forceinline__ void gl2lds16(const __hip_bfloat16* g, __hip_bfloat16* l) {
    __builtin_amdgcn_global_load_lds(
        (const __attribute__((address_space(1))) void*)g,
        (__attribute__((address_space(3))) void*)l, 16, 0, 0);
}

// C[M,N] = A[M,K] @ W[N,K]^T, m97-style 128x128 block tile, BK=32.
// 4 waves in 2x2; each wave: 4x4 grid of 16x16x32 MFMAs (64x64 region).
// Staging: global_load_lds dwordx4; wave w stages rows [w*32,w*32+32) of A and B.
template <int M, int N, int K, typename OT>
__global__ __launch_bounds__(256) void gemm128(const __hip_bfloat16* __restrict__ A,
                                               const __hip_bfloat16* __restrict__ W,
                                               OT* __restrict__ C) {
    __shared__ __hip_bfloat16 As[128 * 32];
    __shared__ __hip_bfloat16 Bs[128 * 32];
    const int tid  = threadIdx.x;
    const int wid  = tid >> 6;
    const int lane = tid & 63;
    const int quad = lane >> 4;
    const int l16  = lane & 15;
    constexpr int NB = N / 128;
    const int bm = blockIdx.x / NB;
    const int bn = blockIdx.x % NB;
    const int wr = wid >> 1, wc = wid & 1;

    const int srow = wid * 32 + (lane >> 2);   // staged row (first 16-row group)
    const int scol = (lane & 3) * 8;           // 8 bf16 = 16B per lane
    const __hip_bfloat16* gA = A + (size_t)(bm * 128 + srow) * K + scol;
    const __hip_bfloat16* gB = W + (size_t)(bn * 128 + srow) * K + scol;
    __hip_bfloat16* lA = &As[(wid * 32) * 32];
    __hip_bfloat16* lB = &Bs[(wid * 32) * 32];

    f32x4 acc[4][4] = {};

    for (int k0 = 0; k0 < K; k0 += 32) {
        __syncthreads();  // prev-iter LDS reads done
        gl2lds16(gA + k0,                  lA);
        gl2lds16(gA + (size_t)16 * K + k0, lA + 16 * 32);
        gl2lds16(gB + k0,                  lB);
        gl2lds16(gB + (size_t)16 * K + k0, lB + 16 * 32);
        __syncthreads();  // staging complete (vmcnt drained by barrier)

        bf16x8 af[4], bf[4];
#pragma unroll
        for (int mi = 0; mi < 4; ++mi)
            af[mi] = *reinterpret_cast<const bf16x8*>(&As[(wr * 64 + mi * 16 + l16) * 32 + quad * 8]);
#pragma unroll
        for (int ni = 0; ni < 4; ++ni)
            bf[ni] = *reinterpret_cast<const bf16x8*>(&Bs[(wc * 64 + ni * 16 + l16) * 32 + quad * 8]);
#pragma unroll
        for (int mi = 0; mi < 4; ++mi)
#pragma unroll
            for (int ni = 0; ni < 4; ++ni)
                acc[mi][ni] = __builtin_amdgcn_mfma_f32_16x16x32_bf16(af[mi], bf[ni], acc[mi][ni], 0, 0, 0);
    }

#pragma unroll
    for (int mi = 0; mi < 4; ++mi)
#pragma unroll
        for (int ni = 0; ni < 4; ++ni) {
            const size_t row0 = (size_t)(bm * 128 + wr * 64 + mi * 16 + quad * 4);
            const size_t col  = (size_t)(bn * 128 + wc * 64 + ni * 16 + l16);
#pragma unroll
            for (int r = 0; r < 4; ++r) {
                if constexpr (__is_same(OT, float))
                    C[(row0 + r) * N + col] = acc[mi][ni][r];
                else
                    C[(row0 + r) * N + col] = __float2bfloat16(acc[mi][ni][r]);
            }
        }
}

#define SV 104  // VT/PT leading stride in ushorts (dword stride 52 == 20 mod 32: spreads banks)

// MFMA flash attention v2: 64-key tiles, K/V register prefetch, causal pairing.
// Block = (b, h, qblk pair {j, 31-j}); wave = 16 q-rows. S^T = K·Q^T (C-layout:
// key=quad*4+r, q=l16 -> per-lane softmax state). PV via LDS: VT[dh][key], PT[q][key].
__global__ __launch_bounds__(256) void attn_mfma2(const __hip_bfloat16* __restrict__ Q,
                                                  const __hip_bfloat16* __restrict__ Km,
                                                  const __hip_bfloat16* __restrict__ Vm,
                                                  __hip_bfloat16* __restrict__ O) {
    __shared__ unsigned short VT[64 * SV];       // V^T: [dh][key-local 0..63]
    __shared__ unsigned short PT[4][16 * SV];    // per-wave P: [q][key-local]

    const int tid  = threadIdx.x;
    const int wid  = tid >> 6;
    const int lane = tid & 63;
    const int quad = lane >> 4;
    const int l16  = lane & 15;

    const int pair = blockIdx.x & 15;            // 16 pairs per (b,h)
    const int bh   = blockIdx.x >> 4;
    const int h    = bh & 15;
    const int b    = bh >> 4;
    const size_t base = (size_t)b * Sz * Dz + (size_t)h * DHz;

    // V staging map: thread covers keys {vkey, vkey+1} (per 32-key half) x 4 dh
    const int vkey = (tid & 15) * 2;
    const int vdh  = (tid >> 4) * 4;
    const __hip_bfloat16* vbase = Vm + base + vdh;

    ushort4 va0, vb0, va1, vb1;                  // V prefetch regs (2 halves)
    bf16x8  kf[4][2];                            // K frags: 4 key-subtiles x 2 dh-halves

    auto loadKV = [&](int kn) {
        va0 = *reinterpret_cast<const ushort4*>(vbase + (size_t)(kn + vkey) * Dz);
        vb0 = *reinterpret_cast<const ushort4*>(vbase + (size_t)(kn + vkey + 1) * Dz);
        va1 = *reinterpret_cast<const ushort4*>(vbase + (size_t)(kn + 32 + vkey) * Dz);
        vb1 = *reinterpret_cast<const ushort4*>(vbase + (size_t)(kn + 32 + vkey + 1) * Dz);
#pragma unroll
        for (int s = 0; s < 4; ++s) {
            const __hip_bfloat16* kp = Km + base + (size_t)(kn + s * 16 + l16) * Dz + quad * 8;
            kf[s][0] = *reinterpret_cast<const bf16x8*>(kp);
            kf[s][1] = *reinterpret_cast<const bf16x8*>(kp + 32);
        }
    };

#pragma unroll 1
    for (int p = 0; p < 2; ++p) {
        const int qblk  = (p == 0) ? pair : 31 - pair;
        const int q0    = qblk * 64 + wid * 16;
        const int niter = qblk + 1;

        const __hip_bfloat16* qp = Q + base + (size_t)(q0 + l16) * Dz + quad * 8;
        const bf16x8 qf0 = *reinterpret_cast<const bf16x8*>(qp);
        const bf16x8 qf1 = *reinterpret_cast<const bf16x8*>(qp + 32);

        float m = -1e30f, l = 0.f;
        f32x4 o0 = {0.f,0.f,0.f,0.f}, o1 = {0.f,0.f,0.f,0.f};
        f32x4 o2 = {0.f,0.f,0.f,0.f}, o3 = {0.f,0.f,0.f,0.f};

        if (p == 0) loadKV(0);  // p==1 start tile was prefetched at end of p==0

#pragma unroll 1
        for (int it = 0; it < niter; ++it) {
            const int k0 = it * 64;

            __syncthreads();  // all waves done reading previous VT
            {
                *reinterpret_cast<ushort2*>(&VT[(vdh + 0) * SV + vkey])      = make_ushort2(va0.x, vb0.x);
                *reinterpret_cast<ushort2*>(&VT[(vdh + 1) * SV + vkey])      = make_ushort2(va0.y, vb0.y);
                *reinterpret_cast<ushort2*>(&VT[(vdh + 2) * SV + vkey])      = make_ushort2(va0.z, vb0.z);
                *reinterpret_cast<ushort2*>(&VT[(vdh + 3) * SV + vkey])      = make_ushort2(va0.w, vb0.w);
                *reinterpret_cast<ushort2*>(&VT[(vdh + 0) * SV + 32 + vkey]) = make_ushort2(va1.x, vb1.x);
                *reinterpret_cast<ushort2*>(&VT[(vdh + 1) * SV + 32 + vkey]) = make_ushort2(va1.y, vb1.y);
                *reinterpret_cast<ushort2*>(&VT[(vdh + 2) * SV + 32 + vkey]) = make_ushort2(va1.z, vb1.z);
                *reinterpret_cast<ushort2*>(&VT[(vdh + 3) * SV + 32 + vkey]) = make_ushort2(va1.w, vb1.w);
            }
            __syncthreads();  // VT ready

            // S^T = K·Q^T : 8 MFMAs (4 key-subtiles x 2 dh-halves)
            f32x4 st[4] = {};
#pragma unroll
            for (int s = 0; s < 4; ++s) {
                st[s] = __builtin_amdgcn_mfma_f32_16x16x32_bf16(kf[s][0], qf0, st[s], 0, 0, 0);
                st[s] = __builtin_amdgcn_mfma_f32_16x16x32_bf16(kf[s][1], qf1, st[s], 0, 0, 0);
            }

            // prefetch next tile (kf/V regs are dead now) — hides global latency
            const bool more = (it + 1 < niter);
            if (more)            loadKV(k0 + 64);
            else if (p == 0)     loadKV(0);

            // softmax over 16 per-lane scores (q = l16, keys = s*16+quad*4+r)
            float sv[16];
            if (it == niter - 1) {           // block-uniform branch: diagonal tile
                const int qrow = q0 + l16;
#pragma unroll
                for (int s = 0; s < 4; ++s)
#pragma unroll
                    for (int r = 0; r < 4; ++r) {
                        const int key = k0 + s * 16 + quad * 4 + r;
                        sv[s * 4 + r] = (key <= qrow) ? st[s][r] * 0.125f : -1e30f;
                    }
            } else {
#pragma unroll
                for (int s = 0; s < 4; ++s)
#pragma unroll
                    for (int r = 0; r < 4; ++r) sv[s * 4 + r] = st[s][r] * 0.125f;
            }

            float tmax = sv[0];
#pragma unroll
            for (int i = 1; i < 16; ++i) tmax = fmaxf(tmax, sv[i]);
            tmax = fmaxf(tmax, __shfl_xor(tmax, 16, 64));
            tmax = fmaxf(tmax, __shfl_xor(tmax, 32, 64));
            const float mnew  = fmaxf(m, tmax);
            const float alpha = __expf(m - mnew);
            m = mnew;

            float psum = 0.f;
            unsigned short pb[16];
#pragma unroll
            for (int i = 0; i < 16; ++i) {
                const float pv = __expf(sv[i] - mnew);
                psum += pv;
                union { __hip_bfloat16 hh; unsigned short uu; } cv;
                cv.hh = __float2bfloat16(pv);
                pb[i] = cv.uu;
            }
            psum += __shfl_xor(psum, 16, 64);
            psum += __shfl_xor(psum, 32, 64);
            l = l * alpha + psum;

            // P^T -> PT[wid][q][key]: keys quad*4+r consecutive -> 8B packed stores
#pragma unroll
            for (int s = 0; s < 4; ++s)
                *reinterpret_cast<ushort4*>(&PT[wid][l16 * SV + s * 16 + quad * 4]) =
                    make_ushort4(pb[4 * s], pb[4 * s + 1], pb[4 * s + 2], pb[4 * s + 3]);

            // rescale O rows (row q-local = quad*4+r; state lives in lane l16=q)
#pragma unroll
            for (int r = 0; r < 4; ++r) {
                const float ar = __shfl(alpha, quad * 4 + r, 64);
                o0[r] *= ar; o1[r] *= ar; o2[r] *= ar; o3[r] *= ar;
            }

            // PV: A = P[q=l16][key=half*32+quad*8+j], B = V^T[dh=s*16+l16][key]
            const bf16x8 pa0 = *reinterpret_cast<const bf16x8*>(&PT[wid][l16 * SV + quad * 8]);
            const bf16x8 pa1 = *reinterpret_cast<const bf16x8*>(&PT[wid][l16 * SV + 32 + quad * 8]);
            const bf16x8 v00 = *reinterpret_cast<const bf16x8*>(&VT[( 0 + l16) * SV + quad * 8]);
            const bf16x8 v01 = *reinterpret_cast<const bf16x8*>(&VT[( 0 + l16) * SV + 32 + quad * 8]);
            const bf16x8 v10 = *reinterpret_cast<const bf16x8*>(&VT[(16 + l16) * SV + quad * 8]);
            const bf16x8 v11 = *reinterpret_cast<const bf16x8*>(&VT[(16 + l16) * SV + 32 + quad * 8]);
            const bf16x8 v20 = *reinterpret_cast<const bf16x8*>(&VT[(32 + l16) * SV + quad * 8]);
            const bf16x8 v21 = *reinterpret_cast<const bf16x8*>(&VT[(32 + l16) * SV + 32 + quad * 8]);
            const bf16x8 v30 = *reinterpret_cast<const bf16x8*>(&VT[(48 + l16) * SV + quad * 8]);
            const bf16x8 v31 = *reinterpret_cast<const bf16x8*>(&VT[(48 + l16) * SV + 32 + quad * 8]);
            o0 = __builtin_amdgcn_mfma_f32_16x16x32_bf16(pa0, v00, o0, 0, 0, 0);
            o0 = __builtin_amdgcn_mfma_f32_16x16x32_bf16(pa1, v01, o0, 0, 0, 0);
            o1 = __builtin_amdgcn_mfma_f32_16x16x32_bf16(pa0, v10, o1, 0, 0, 0);
            o1 = __builtin_amdgcn_mfma_f32_16x16x32_bf16(pa1, v11, o1, 0, 0, 0);
            o2 = __builtin_amdgcn_mfma_f32_16x16x32_bf16(pa0, v20, o2, 0, 0, 0);
            o2 = __builtin_amdgcn_mfma_f32_16x16x32_bf16(pa1, v21, o2, 0, 0, 0);
            o3 = __builtin_amdgcn_mfma_f32_16x16x32_bf16(pa0, v30, o3, 0, 0, 0);
            o3 = __builtin_amdgcn_mfma_f32_16x16x32_bf16(pa1, v31, o3, 0, 0, 0);
        }

        // epilogue: O[q0+quad*4+r][s*16+l16]
#pragma unroll
        for (int r = 0; r < 4; ++r) {
            const float linv = 1.f / __shfl(l, quad * 4 + r, 64);
            __hip_bfloat16* op = O + base + (size_t)(q0 + quad * 4 + r) * Dz + l16;
            op[0]  = __float2bfloat16(o0[r] * linv);
            op[16] = __float2bfloat16(o1[r] * linv);
            op[32] = __float2bfloat16(o2[r] * linv);
            op[48] = __float2bfloat16(o3[r] * linv);
        }
    }
}

extern "C" void kernel_launch(void* const* d_in, const int* in_sizes, int n_in,
                              void* d_out, int out_size, void* d_ws, size_t ws_size,
                              hipStream_t stream) {
    // Inputs fp32, output fp32. Internal compute bf16.
    const float* x  = (const float*)d_in[0];
    const float* wq = (const float*)d_in[1];
    const float* wk = (const float*)d_in[2];
    const float* wv = (const float*)d_in[3];
    const float* wo = (const float*)d_in[4];
    float* out = (float*)d_out;

    constexpr int TOK = Bz * Sz * Dz;   // 8,388,608
    constexpr int WEL = Dz * Dz;        // 1,048,576

    // ws: xb | wqb | wkb | wvb | wob | Qb | Kb (56 MB). Vb in d_out scratch; Ob aliases xb.
    __hip_bfloat16* xb  = (__hip_bfloat16*)d_ws;
    __hip_bfloat16* wqb = xb  + TOK;
    __hip_bfloat16* wkb = wqb + WEL;
    __hip_bfloat16* wvb = wkb + WEL;
    __hip_bfloat16* wob = wvb + WEL;
    __hip_bfloat16* Qb  = wob + WEL;
    __hip_bfloat16* Kb  = Qb + TOK;
    __hip_bfloat16* Vb  = (__hip_bfloat16*)d_out;  // dead before final GEMM overwrites d_out
    __hip_bfloat16* Ob  = xb;                      // x dead after QKV GEMMs

    cvt_f32_bf16<<<TOK / 4 / 256, 256, 0, stream>>>(x,  xb,  TOK);
    cvt_f32_bf16<<<WEL / 4 / 256, 256, 0, stream>>>(wq, wqb, WEL);
    cvt_f32_bf16<<<WEL / 4 / 256, 256, 0, stream>>>(wk, wkb, WEL);
    cvt_f32_bf16<<<WEL / 4 / 256, 256, 0, stream>>>(wv, wvb, WEL);
    cvt_f32_bf16<<<WEL / 4 / 256, 256, 0, stream>>>(wo, wob, WEL);

    constexpr int M = Bz * Sz;                       // 8192
    constexpr int GB = (M / 128) * (Dz / 128);       // 512 blocks

    gemm128<M, Dz, Dz, __hip_bfloat16><<<GB, 256, 0, stream>>>(xb, wqb, Qb);
    gemm128<M, Dz, Dz, __hip_bfloat16><<<GB, 256, 0, stream>>>(xb, wkb, Kb);
    gemm128<M, Dz, Dz, __hip_bfloat16><<<GB, 256, 0, stream>>>(xb, wvb, Vb);

    const int ATTN_BLOCKS = Bz * Hz * 16;            // 1024 (paired q-blocks)
    attn_mfma2<<<ATTN_BLOCKS, 256, 0, stream>>>(Qb, Kb, Vb, Ob);

    gemm128<M, Dz, Dz, float><<<GB, 256, 0, stream>>>(Ob, wob, out);
}

// Round 6
// 366.840 us; speedup vs baseline: 26.5873x; 1.0748x over previous
//
#include <hip/hip_runtime.h>
#include <hip/hip_bf16.h>

#define Bz 4
#define Sz 2048
#define Dz 1024
#define Hz 16
#define DHz 64

typedef __bf16 bf16x8 __attribute__((ext_vector_type(8)));
typedef float f32x4 __attribute__((ext_vector_type(4)));

// LDS-only barrier: waits DS ops, leaves global loads in flight (unlike
// __syncthreads, which drains vmcnt(0) and defeats register prefetch).
#define BAR_LGKM() asm volatile("s_waitcnt lgkmcnt(0)\n\ts_barrier" ::: "memory")

// fp32 -> bf16 elementwise cast (RTN), n % 4 == 0.
__global__ __launch_bounds__(256) void cvt_f32_bf16(const float* __restrict__ src,
                                                    __hip_bfloat16* __restrict__ dst, int n) {
    int i = (blockIdx.x * 256 + threadIdx.x) * 4;
    if (i >= n) return;
    float4 f = *reinterpret_cast<const float4*>(src + i);
    dst[i + 0] = __float2bfloat16(f.x);
    dst[i + 1] = __float2bfloat16(f.y);
    dst[i + 2] = __float2bfloat16(f.z);
    dst[i + 3] = __float2bfloat16(f.w);
}

// 4 weight matrices (Dz*Dz each) -> contiguous bf16 dst in one launch.
__global__ __launch_bounds__(256) void cvt_w4(const float* __restrict__ w0, const float* __restrict__ w1,
                                              const float* __restrict__ w2, const float* __restrict__ w3,
                                              __hip_bfloat16* __restrict__ dst) {
    constexpr int WEL = Dz * Dz;  // 1<<20
    int i = (blockIdx.x * 256 + threadIdx.x) * 4;
    const int which = i >> 20;
    const float* src = (which == 0) ? w0 : (which == 1) ? w1 : (which == 2) ? w2 : w3;
    float4 f = *reinterpret_cast<const float4*>(src + (i & (WEL - 1)));
    dst[i + 0] = __float2bfloat16(f.x);
    dst[i + 1] = __float2bfloat16(f.y);
    dst[i + 2] = __float2bfloat16(f.z);
    dst[i + 3] = __float2bfloat16(f.w);
}

// async global -> LDS, 16 bytes per lane; LDS dest = uniform base + lane*16.
__device__ __forceinline__ void gl2lds16(const __hip_bfloat16* g, __hip_bfloat16* l) {
    __builtin_amdgcn_global_load_lds(
        (const __attribute__((address_space(1))) void*)g,
        (__attribute__((address_space(3))) void*)l, 16, 0, 0);
}

// Shared 128x128 GEMM block body (m97 structure, BK=32).
template <int N, int K, typename OT>
__device__ __forceinline__ void gemm128_body(const __hip_bfloat16* __restrict__ A,
                                             const __hip_bfloat16* __restrict__ W,
                                             OT* __restrict__ C, int bm, int bn,
                                             __hip_bfloat16* As, __hip_bfloat16* Bs) {
    const int tid  = threadIdx.x;
    const int wid  = tid >> 6;
    const int lane = tid & 63;
    const int quad = lane >> 4;
    const int l16  = lane & 15;
    const int wr = wid >> 1, wc = wid & 1;

    const int srow = wid * 32 + (lane >> 2);
    const int scol = (lane & 3) * 8;
    const __hip_bfloat16* gA = A + (size_t)(bm * 128 + srow) * K + scol;
    const __hip_bfloat16* gB = W + (size_t)(bn * 128 + srow) * K + scol;
    __hip_bfloat16* lA = &As[(wid * 32) * 32];
    __hip_bfloat16* lB = &Bs[(wid * 32) * 32];

    f32x4 acc[4][4] = {};

    for (int k0 = 0; k0 < K; k0 += 32) {
        __syncthreads();
        gl2lds16(gA + k0,                  lA);
        gl2lds16(gA + (size_t)16 * K + k0, lA + 16 * 32);
        gl2lds16(gB + k0,                  lB);
        gl2lds16(gB + (size_t)16 * K + k0, lB + 16 * 32);
        __syncthreads();

        bf16x8 af[4], bf[4];
#pragma unroll
        for (int mi = 0; mi < 4; ++mi)
            af[mi] = *reinterpret_cast<const bf16x8*>(&As[(wr * 64 + mi * 16 + l16) * 32 + quad * 8]);
#pragma unroll
        for (int ni = 0; ni < 4; ++ni)
            bf[ni] = *reinterpret_cast<const bf16x8*>(&Bs[(wc * 64 + ni * 16 + l16) * 32 + quad * 8]);
#pragma unroll
        for (int mi = 0; mi < 4; ++mi)
#pragma unroll
            for (int ni = 0; ni < 4; ++ni)
                acc[mi][ni] = __builtin_amdgcn_mfma_f32_16x16x32_bf16(af[mi], bf[ni], acc[mi][ni], 0, 0, 0);
    }

#pragma unroll
    for (int mi = 0; mi < 4; ++mi)
#pragma unroll
        for (int ni = 0; ni < 4; ++ni) {
            const size_t row0 = (size_t)(bm * 128 + wr * 64 + mi * 16 + quad * 4);
            const size_t col  = (size_t)(bn * 128 + wc * 64 + ni * 16 + l16);
#pragma unroll
            for (int r = 0; r < 4; ++r) {
                if constexpr (__is_same(OT, float))
                    C[(row0 + r) * N + col] = acc[mi][ni][r];
                else
                    C[(row0 + r) * N + col] = __float2bfloat16(acc[mi][ni][r]);
            }
        }
}

template <int M, int N, int K, typename OT>
__global__ __launch_bounds__(256) void gemm128(const __hip_bfloat16* __restrict__ A,
                                               const __hip_bfloat16* __restrict__ W,
                                               OT* __restrict__ C) {
    __shared__ __hip_bfloat16 As[128 * 32];
    __shared__ __hip_bfloat16 Bs[128 * 32];
    constexpr int NB = N / 128;
    gemm128_body<N, K, OT>(A, W, C, blockIdx.x / NB, blockIdx.x % NB, As, Bs);
}

// Fused QKV: grid = 3 * (M/128) * (Dz/128); which = blockIdx%3 so the 3 GEMMs
// sharing an A-tile are adjacent in dispatch order (L2 reuse of A).
template <int M, int K>
__global__ __launch_bounds__(256) void gemm_qkv(const __hip_bfloat16* __restrict__ A,
                                                const __hip_bfloat16* __restrict__ W0,
                                                const __hip_bfloat16* __restrict__ W1,
                                                const __hip_bfloat16* __restrict__ W2,
                                                __hip_bfloat16* __restrict__ C0,
                                                __hip_bfloat16* __restrict__ C1,
                                                __hip_bfloat16* __restrict__ C2) {
    __shared__ __hip_bfloat16 As[128 * 32];
    __shared__ __hip_bfloat16 Bs[128 * 32];
    constexpr int NB = Dz / 128;
    const int which = blockIdx.x % 3;
    const int rem   = blockIdx.x / 3;
    const __hip_bfloat16* W = (which == 0) ? W0 : (which == 1) ? W1 : W2;
    __hip_bfloat16*       C = (which == 0) ? C0 : (which == 1) ? C1 : C2;
    gemm128_body<Dz, K, __hip_bfloat16>(A, W, C, rem / NB, rem % NB, As, Bs);
}

#define SV 104  // VT/PT leading stride (ushorts); b128 read pattern is bank-optimal

// MFMA flash attention v3: 64-key tiles, K/V register prefetch, causal pairing,
// lgkm-only barriers (prefetch survives the barrier), XCD-local block mapping.
__global__ __launch_bounds__(256) void attn_mfma3(const __hip_bfloat16* __restrict__ Q,
                                                  const __hip_bfloat16* __restrict__ Km,
                                                  const __hip_bfloat16* __restrict__ Vm,
                                                  __hip_bfloat16* __restrict__ O) {
    __shared__ unsigned short VT[64 * SV];       // V^T: [dh][key-local 0..63]
    __shared__ unsigned short PT[4][16 * SV];    // per-wave P: [q][key-local]

    const int tid  = threadIdx.x;
    const int wid  = tid >> 6;
    const int lane = tid & 63;
    const int quad = lane >> 4;
    const int l16  = lane & 15;

    // XCD-local mapping: all 16 pair-blocks of a (b,h) share blockIdx%8 -> same XCD L2.
    const int xcd  = blockIdx.x & 7;
    const int j    = blockIdx.x >> 3;            // 0..127
    const int bh   = xcd * 8 + (j >> 4);         // 0..63
    const int pair = j & 15;
    const int h    = bh & 15;
    const int b    = bh >> 4;
    const size_t base = (size_t)b * Sz * Dz + (size_t)h * DHz;

    const int vkey = (tid & 15) * 2;
    const int vdh  = (tid >> 4) * 4;
    const __hip_bfloat16* vbase = Vm + base + vdh;

    ushort4 va0, vb0, va1, vb1;                  // V prefetch regs (2 halves)
    bf16x8  kf[4][2];                            // K frags: 4 key-subtiles x 2 dh-halves

    auto loadKV = [&](int kn) {
        va0 = *reinterpret_cast<const ushort4*>(vbase + (size_t)(kn + vkey) * Dz);
        vb0 = *reinterpret_cast<const ushort4*>(vbase + (size_t)(kn + vkey + 1) * Dz);
        va1 = *reinterpret_cast<const ushort4*>(vbase + (size_t)(kn + 32 + vkey) * Dz);
        vb1 = *reinterpret_cast<const ushort4*>(vbase + (size_t)(kn + 32 + vkey + 1) * Dz);
#pragma unroll
        for (int s = 0; s < 4; ++s) {
            const __hip_bfloat16* kp = Km + base + (size_t)(kn + s * 16 + l16) * Dz + quad * 8;
            kf[s][0] = *reinterpret_cast<const bf16x8*>(kp);
            kf[s][1] = *reinterpret_cast<const bf16x8*>(kp + 32);
        }
    };

#pragma unroll 1
    for (int p = 0; p < 2; ++p) {
        const int qblk  = (p == 0) ? pair : 31 - pair;
        const int q0    = qblk * 64 + wid * 16;
        const int niter = qblk + 1;

        const __hip_bfloat16* qp = Q + base + (size_t)(q0 + l16) * Dz + quad * 8;
        const bf16x8 qf0 = *reinterpret_cast<const bf16x8*>(qp);
        const bf16x8 qf1 = *reinterpret_cast<const bf16x8*>(qp + 32);

        float m = -1e30f, l = 0.f;
        f32x4 o0 = {0.f,0.f,0.f,0.f}, o1 = {0.f,0.f,0.f,0.f};
        f32x4 o2 = {0.f,0.f,0.f,0.f}, o3 = {0.f,0.f,0.f,0.f};

        if (p == 0) loadKV(0);  // p==1 start tile prefetched at end of p==0

#pragma unroll 1
        for (int it = 0; it < niter; ++it) {
            const int k0 = it * 64;

            BAR_LGKM();  // all waves done reading previous VT (lgkm only)
            {
                *reinterpret_cast<ushort2*>(&VT[(vdh + 0) * SV + vkey])      = make_ushort2(va0.x, vb0.x);
                *reinterpret_cast<ushort2*>(&VT[(vdh + 1) * SV + vkey])      = make_ushort2(va0.y, vb0.y);
                *reinterpret_cast<ushort2*>(&VT[(vdh + 2) * SV + vkey])      = make_ushort2(va0.z, vb0.z);
                *reinterpret_cast<ushort2*>(&VT[(vdh + 3) * SV + vkey])      = make_ushort2(va0.w, vb0.w);
                *reinterpret_cast<ushort2*>(&VT[(vdh + 0) * SV + 32 + vkey]) = make_ushort2(va1.x, vb1.x);
                *reinterpret_cast<ushort2*>(&VT[(vdh + 1) * SV + 32 + vkey]) = make_ushort2(va1.y, vb1.y);
                *reinterpret_cast<ushort2*>(&VT[(vdh + 2) * SV + 32 + vkey]) = make_ushort2(va1.z, vb1.z);
                *reinterpret_cast<ushort2*>(&VT[(vdh + 3) * SV + 32 + vkey]) = make_ushort2(va1.w, vb1.w);
            }
            BAR_LGKM();  // VT visible to all waves

            // S^T = K·Q^T : 8 MFMAs
            f32x4 st[4] = {};
#pragma unroll
            for (int s = 0; s < 4; ++s) {
                st[s] = __builtin_amdgcn_mfma_f32_16x16x32_bf16(kf[s][0], qf0, st[s], 0, 0, 0);
                st[s] = __builtin_amdgcn_mfma_f32_16x16x32_bf16(kf[s][1], qf1, st[s], 0, 0, 0);
            }

            // prefetch next K/V tile — stays in flight across the lgkm barriers
            const bool more = (it + 1 < niter);
            if (more)        loadKV(k0 + 64);
            else if (p == 0) loadKV(0);

            // softmax over 16 per-lane scores (q = l16, keys = s*16+quad*4+r)
            float sv[16];
            if (it == niter - 1) {               // block-uniform branch: diagonal tile
                const int qrow = q0 + l16;
#pragma unroll
                for (int s = 0; s < 4; ++s)
#pragma unroll
                    for (int r = 0; r < 4; ++r) {
                        const int key = k0 + s * 16 + quad * 4 + r;
                        sv[s * 4 + r] = (key <= qrow) ? st[s][r] * 0.125f : -1e30f;
                    }
            } else {
#pragma unroll
                for (int s = 0; s < 4; ++s)
#pragma unroll
                    for (int r = 0; r < 4; ++r) sv[s * 4 + r] = st[s][r] * 0.125f;
            }

            float tmax = sv[0];
#pragma unroll
            for (int i = 1; i < 16; ++i) tmax = fmaxf(tmax, sv[i]);
            tmax = fmaxf(tmax, __shfl_xor(tmax, 16, 64));
            tmax = fmaxf(tmax, __shfl_xor(tmax, 32, 64));
            const float mnew  = fmaxf(m, tmax);
            const float alpha = __expf(m - mnew);
            m = mnew;

            float psum = 0.f;
            unsigned short pb[16];
#pragma unroll
            for (int i = 0; i < 16; ++i) {
                const float pv = __expf(sv[i] - mnew);
                psum += pv;
                union { __hip_bfloat16 hh; unsigned short uu; } cv;
                cv.hh = __float2bfloat16(pv);
                pb[i] = cv.uu;
            }
            psum += __shfl_xor(psum, 16, 64);
            psum += __shfl_xor(psum, 32, 64);
            l = l * alpha + psum;

            // P^T -> PT[wid][q][key] (8B packed stores; per-wave buffer, no barrier)
#pragma unroll
            for (int s = 0; s < 4; ++s)
                *reinterpret_cast<ushort4*>(&PT[wid][l16 * SV + s * 16 + quad * 4]) =
                    make_ushort4(pb[4 * s], pb[4 * s + 1], pb[4 * s + 2], pb[4 * s + 3]);

            // rescale O rows (row q-local = quad*4+r; state lives in lane l16=q)
#pragma unroll
            for (int r = 0; r < 4; ++r) {
                const float ar = __shfl(alpha, quad * 4 + r, 64);
                o0[r] *= ar; o1[r] *= ar; o2[r] *= ar; o3[r] *= ar;
            }

            // PV: A = P[q=l16][key=half*32+quad*8+j], B = V^T[dh=s*16+l16][key]
            const bf16x8 pa0 = *reinterpret_cast<const bf16x8*>(&PT[wid][l16 * SV + quad * 8]);
            const bf16x8 pa1 = *reinterpret_cast<const bf16x8*>(&PT[wid][l16 * SV + 32 + quad * 8]);
            const bf16x8 v00 = *reinterpret_cast<const bf16x8*>(&VT[( 0 + l16) * SV + quad * 8]);
            const bf16x8 v01 = *reinterpret_cast<const bf16x8*>(&VT[( 0 + l16) * SV + 32 + quad * 8]);
            const bf16x8 v10 = *reinterpret_cast<const bf16x8*>(&VT[(16 + l16) * SV + quad * 8]);
            const bf16x8 v11 = *reinterpret_cast<const bf16x8*>(&VT[(16 + l16) * SV + 32 + quad * 8]);
            const bf16x8 v20 = *reinterpret_cast<const bf16x8*>(&VT[(32 + l16) * SV + quad * 8]);
            const bf16x8 v21 = *reinterpret_cast<const bf16x8*>(&VT[(32 + l16) * SV + 32 + quad * 8]);
            const bf16x8 v30 = *reinterpret_cast<const bf16x8*>(&VT[(48 + l16) * SV + quad * 8]);
            const bf16x8 v31 = *reinterpret_cast<const bf16x8*>(&VT[(48 + l16) * SV + 32 + quad * 8]);
            o0 = __builtin_amdgcn_mfma_f32_16x16x32_bf16(pa0, v00, o0, 0, 0, 0);
            o0 = __builtin_amdgcn_mfma_f32_16x16x32_bf16(pa1, v01, o0, 0, 0, 0);
            o1 = __builtin_amdgcn_mfma_f32_16x16x32_bf16(pa0, v10, o1, 0, 0, 0);
            o1 = __builtin_amdgcn_mfma_f32_16x16x32_bf16(pa1, v11, o1, 0, 0, 0);
            o2 = __builtin_amdgcn_mfma_f32_16x16x32_bf16(pa0, v20, o2, 0, 0, 0);
            o2 = __builtin_amdgcn_mfma_f32_16x16x32_bf16(pa1, v21, o2, 0, 0, 0);
            o3 = __builtin_amdgcn_mfma_f32_16x16x32_bf16(pa0, v30, o3, 0, 0, 0);
            o3 = __builtin_amdgcn_mfma_f32_16x16x32_bf16(pa1, v31, o3, 0, 0, 0);
        }

        // epilogue: O[q0+quad*4+r][s*16+l16]
#pragma unroll
        for (int r = 0; r < 4; ++r) {
            const float linv = 1.f / __shfl(l, quad * 4 + r, 64);
            __hip_bfloat16* op = O + base + (size_t)(q0 + quad * 4 + r) * Dz + l16;
            op[0]  = __float2bfloat16(o0[r] * linv);
            op[16] = __float2bfloat16(o1[r] * linv);
            op[32] = __float2bfloat16(o2[r] * linv);
            op[48] = __float2bfloat16(o3[r] * linv);
        }
    }
}

extern "C" void kernel_launch(void* const* d_in, const int* in_sizes, int n_in,
                              void* d_out, int out_size, void* d_ws, size_t ws_size,
                              hipStream_t stream) {
    // Inputs fp32, output fp32. Internal compute bf16.
    const float* x  = (const float*)d_in[0];
    const float* wq = (const float*)d_in[1];
    const float* wk = (const float*)d_in[2];
    const float* wv = (const float*)d_in[3];
    const float* wo = (const float*)d_in[4];
    float* out = (float*)d_out;

    constexpr int TOK = Bz * Sz * Dz;   // 8,388,608
    constexpr int WEL = Dz * Dz;        // 1,048,576

    // ws: xb | wqb | wkb | wvb | wob | Qb | Kb (56 MB). Vb in d_out scratch; Ob aliases xb.
    __hip_bfloat16* xb  = (__hip_bfloat16*)d_ws;
    __hip_bfloat16* wqb = xb  + TOK;
    __hip_bfloat16* wkb = wqb + WEL;
    __hip_bfloat16* wvb = wkb + WEL;
    __hip_bfloat16* wob = wvb + WEL;
    __hip_bfloat16* Qb  = wob + WEL;
    __hip_bfloat16* Kb  = Qb + TOK;
    __hip_bfloat16* Vb  = (__hip_bfloat16*)d_out;  // dead before final GEMM overwrites d_out
    __hip_bfloat16* Ob  = xb;                      // x dead after QKV GEMM

    cvt_f32_bf16<<<TOK / 4 / 256, 256, 0, stream>>>(x, xb, TOK);
    cvt_w4<<<4 * WEL / 4 / 256, 256, 0, stream>>>(wq, wk, wv, wo, wqb);

    constexpr int M = Bz * Sz;                       // 8192
    constexpr int GB = (M / 128) * (Dz / 128);       // 512

    gemm_qkv<M, Dz><<<3 * GB, 256, 0, stream>>>(xb, wqb, wkb, wvb, Qb, Kb, Vb);

    const int ATTN_BLOCKS = Bz * Hz * 16;            // 1024 (paired q-blocks)
    attn_mfma3<<<ATTN_BLOCKS, 256, 0, stream>>>(Qb, Kb, Vb, Ob);

    gemm128<M, Dz, Dz, float><<<GB, 256, 0, stream>>>(Ob, wob, out);
}